// Round 1
// baseline (159.120 us; speedup 1.0000x reference)
//
#include <hip/hip_runtime.h>
#include <hip/hip_bf16.h>
#include <stdint.h>

typedef __attribute__((ext_vector_type(8))) __bf16 bf16x8;
typedef __attribute__((ext_vector_type(4))) float f32x4;

// Problem constants (B=1024, L=512, F=256, H=512, K=64)
#define NBATCH 1024
#define SEQL   512
#define FDIM   256
#define HDIM   512
#define KNN    64
#define NODES  65
#define ROWSTR 512           // bytes per A-tile row (256 bf16)

__device__ __forceinline__ unsigned short f32_bf16(float f) {
    unsigned int u = __float_as_uint(f);
    unsigned int r = u + 0x7FFFu + ((u >> 16) & 1u);
    return (unsigned short)(r >> 16);
}

// ---------------------------------------------------------------------------
// Kernel 1: convert W1r and W1l to bf16 into Wb rows [0..511]=W1r, [512..1023]=W1l
// (verbatim, validated)
// ---------------------------------------------------------------------------
__global__ __launch_bounds__(256) void convw_kernel(
    const float* __restrict__ W1r, const float* __restrict__ W1l,
    unsigned short* __restrict__ Wb)
{
    int i = (blockIdx.x * 256 + threadIdx.x) * 8;      // [0, 262144)
    const float* src = (i < HDIM * FDIM) ? (W1r + i) : (W1l + (i - HDIM * FDIM));
    float4 a = *reinterpret_cast<const float4*>(src);
    float4 c = *reinterpret_cast<const float4*>(src + 4);
    uint4 t;
    t.x = (unsigned)f32_bf16(a.x) | ((unsigned)f32_bf16(a.y) << 16);
    t.y = (unsigned)f32_bf16(a.z) | ((unsigned)f32_bf16(a.w) << 16);
    t.z = (unsigned)f32_bf16(c.x) | ((unsigned)f32_bf16(c.y) << 16);
    t.w = (unsigned)f32_bf16(c.z) | ((unsigned)f32_bf16(c.w) << 16);
    *reinterpret_cast<uint4*>(Wb + i) = t;
}

// ---------------------------------------------------------------------------
// Kernel 2 (fused, one 256-thread block per batch; 4 blocks/CU co-resident).
// Phases: radix rank-select top-64 -> float4 gather into swizzled bf16 LDS
// A-tile (rows 0..64, row 65 = aggr1) -> per-wave register-B GEMM (4 passes
// of 32 cols) -> fused epilogue.
// ---------------------------------------------------------------------------
__global__ __launch_bounds__(256, 4) void fused_kernel(
    const float* __restrict__ inputs,   // [B,L,F]
    const float* __restrict__ coords,   // [B,L,2]
    const float* __restrict__ targets,  // [B,L,1]
    const int*   __restrict__ lens,     // [B]
    const unsigned short* __restrict__ Wb, // [1024,256] bf16: W1r then W1l
    const float* __restrict__ b1,       // [H]
    const float* __restrict__ W2l,      // [H]
    const float* __restrict__ W2r,      // [H]
    const float* __restrict__ b2,       // [1]
    float* __restrict__ dout)           // [2048]
{
    __shared__ __align__(16) unsigned short ldsA[66 * FDIM];  // 33 KiB, swizzled
    __shared__ __align__(16) int scr4[1024];                  // 4 KiB: hist / part union
    __shared__ int idxs[KNN];
    __shared__ int selS[2];
    __shared__ int wcntS[8];
    __shared__ int nltS;

    const int b    = blockIdx.x;
    const int tid  = threadIdx.x;
    const int lane = tid & 63;
    const int w    = tid >> 6;          // wave 0..3

    const float* cb = coords + (size_t)b * (SEQL * 2);
    const float qx = cb[0], qy = cb[1];
    const int len = lens[b];

    if (tid == 0) {
        dout[b] = b2[0];                                  // bias init; epilogue accumulates
        dout[NBATCH + b] = targets[(size_t)b * SEQL];     // y head
    }

    // ---- phase 1a: 32-bit distance keys for candidates tid and tid+256 ----
    unsigned int k0 = 0xFFFFFFFFu, k1 = 0xFFFFFFFFu;
    {
        float dx = cb[2 * (tid + 1)]     - qx;
        float dy = cb[2 * (tid + 1) + 1] - qy;
        float d2 = dx * dx + dy * dy;
        if (tid < len - 1) k0 = __float_as_uint(d2);
        int c1 = tid + 256;
        if (c1 < SEQL - 1) {
            float ex = cb[2 * (c1 + 1)]     - qx;
            float ey = cb[2 * (c1 + 1) + 1] - qy;
            float e2 = ex * ex + ey * ey;
            if (c1 < len - 1) k1 = __float_as_uint(e2);
        }
    }

    // ---- phase 1b: radix rank-select — exact 64th-smallest key T ----
    unsigned int T = 0;
    int rem = KNN - 1;                   // rank of T within active set
    bool a0 = true, a1 = true;
    #pragma unroll 1
    for (int rd = 0; rd < 4; ++rd) {
        const int shift = 24 - rd * 8;
        scr4[tid] = 0;                   // 256 threads clear 256 bins
        __syncthreads();
        if (a0) atomicAdd(&scr4[(k0 >> shift) & 255u], 1);
        if (a1) atomicAdd(&scr4[(k1 >> shift) & 255u], 1);
        __syncthreads();
        if (tid < 64) {                  // wave 0 scans 256 bins (4 per lane)
            int4 hv = *reinterpret_cast<const int4*>(&scr4[tid * 4]);
            int s = hv.x + hv.y + hv.z + hv.w;
            int inc = s;
            #pragma unroll
            for (int off = 1; off < 64; off <<= 1) {
                int t = __shfl_up(inc, off, 64);
                if (lane >= off) inc += t;
            }
            int before = inc - s;
            if (before <= rem && rem < inc) {   // unique crossing lane
                int rr = rem - before;
                int d = tid * 4;
                if (rr >= hv.x) { rr -= hv.x; ++d;
                    if (rr >= hv.y) { rr -= hv.y; ++d;
                        if (rr >= hv.z) { rr -= hv.z; ++d; } } }
                selS[0] = d; selS[1] = rr;
            }
        }
        __syncthreads();
        const unsigned int d = (unsigned int)selS[0];
        rem = selS[1];
        T |= d << shift;
        a0 = a0 && (((k0 >> shift) & 255u) == d);
        a1 = a1 && (((k1 >> shift) & 255u) == d);
    }

    // ---- phase 1c: compaction. All key<T, then ties==T in candidate order ----
    if (tid == 0) nltS = 0;
    __syncthreads();
    if (k0 < T) idxs[atomicAdd(&nltS, 1)] = tid;
    if (k1 < T) idxs[atomicAdd(&nltS, 1)] = tid + 256;
    __syncthreads();
    {
        const int nlt = nltS;
        unsigned long long m0 = __ballot(k0 == T);
        unsigned long long m1 = __ballot(k1 == T);
        if (lane == 0) { wcntS[w] = (int)__popcll(m0); wcntS[4 + w] = (int)__popcll(m1); }
        __syncthreads();
        const int need = KNN - nlt;
        int base0 = 0;
        int base1 = wcntS[0] + wcntS[1] + wcntS[2] + wcntS[3];
        for (int k = 0; k < w; ++k) { base0 += wcntS[k]; base1 += wcntS[4 + k]; }
        unsigned long long below = (1ull << lane) - 1ull;
        if (k0 == T) {
            int r = base0 + (int)__popcll(m0 & below);
            if (r < need) idxs[nlt + r] = tid;
        }
        if (k1 == T) {
            int r = base1 + (int)__popcll(m1 & below);
            if (r < need) idxs[nlt + r] = tid + 256;
        }
    }
    __syncthreads();

    const int c4 = lane;              // float4 column 0..63
    const int g0 = w;                 // row phase 0..3

#define STROW(row, v) do {                                                   \
    int off_ = (row) * ROWSTR + c4 * 8; off_ ^= ((row) & 7) << 4;            \
    uint2 pk_;                                                               \
    pk_.x = (unsigned)f32_bf16((v).x) | ((unsigned)f32_bf16((v).y) << 16);   \
    pk_.y = (unsigned)f32_bf16((v).z) | ((unsigned)f32_bf16((v).w) << 16);   \
    *reinterpret_cast<uint2*>(reinterpret_cast<char*>(ldsA) + off_) = pk_;   \
} while (0)

    // ---- phase 2: float4 gather, rows r = g0+4m (+row 64 by g0==0) ----
    {
        const float* xb = inputs + (size_t)b * SEQL * FDIM + c4 * 4;
        float4 sum = {0.f, 0.f, 0.f, 0.f};
        #pragma unroll 1
        for (int kk = 0; kk < 16; kk += 4) {
            float4 v[4];
            #pragma unroll
            for (int q = 0; q < 4; ++q) {
                int r = g0 + (kk + q) * 4;
                int src = (r == 0) ? 0 : idxs[r - 1];
                v[q] = *reinterpret_cast<const float4*>(xb + (size_t)src * FDIM);
            }
            #pragma unroll
            for (int q = 0; q < 4; ++q) {
                int r = g0 + (kk + q) * 4;
                sum.x += v[q].x; sum.y += v[q].y; sum.z += v[q].z; sum.w += v[q].w;
                STROW(r, v[q]);
            }
        }
        if (g0 == 0) {
            float4 v = *reinterpret_cast<const float4*>(xb + (size_t)idxs[63] * FDIM);
            sum.x += v.x; sum.y += v.y; sum.z += v.z; sum.w += v.w;
            STROW(64, v);
        }
        float4* part = reinterpret_cast<float4*>(scr4);   // [4][64], reuses hist space
        part[g0 * 64 + c4] = sum;
    }
    __syncthreads();
    if (tid < 64) {                              // row 65 = aggr1 (bf16)
        const float4* part = reinterpret_cast<const float4*>(scr4);
        float sx = 0.f, sy = 0.f, sz = 0.f, sw2 = 0.f;
        #pragma unroll
        for (int q = 0; q < 4; ++q) {
            float4 p = part[q * 64 + tid];
            sx += p.x; sy += p.y; sz += p.z; sw2 += p.w;
        }
        const float inv = 1.0f / 65.0f;
        uint2 pk;
        pk.x = (unsigned)f32_bf16(sx * inv) | ((unsigned)f32_bf16(sy * inv) << 16);
        pk.y = (unsigned)f32_bf16(sz * inv) | ((unsigned)f32_bf16(sw2 * inv) << 16);
        int off = 65 * ROWSTR + tid * 8; off ^= 0x10;     // (65&7)<<4
        *reinterpret_cast<uint2*>(reinterpret_cast<char*>(ldsA) + off) = pk;
    }
    __syncthreads();
#undef STROW

    // ---- phase 3: GEMM + epilogue, per wave over 4 passes of 32 cols ----
    const int cl = lane & 15, g = lane >> 4;

    #pragma unroll 1
    for (int p = 0; p < 4; ++p) {
        const int cbase = w * 128 + p * 32;

        f32x4 acc[5][2], accU[2];
        #pragma unroll
        for (int m = 0; m < 5; ++m) {
            acc[m][0] = f32x4{0.f, 0.f, 0.f, 0.f};
            acc[m][1] = f32x4{0.f, 0.f, 0.f, 0.f};
        }
        accU[0] = f32x4{0.f, 0.f, 0.f, 0.f};
        accU[1] = f32x4{0.f, 0.f, 0.f, 0.f};

        const char* bR0 = (const char*)Wb + (size_t)(cbase + cl) * ROWSTR + g * 16;
        const char* bR1 = bR0 + 16 * ROWSTR;
        const char* bL0 = bR0 + (size_t)HDIM * ROWSTR;       // W1l rows at +512
        const char* bL1 = bL0 + 16 * ROWSTR;

        #pragma unroll
        for (int kc = 0; kc < 4; ++kc) {
            #pragma unroll
            for (int s = 0; s < 2; ++s) {
                const int kb = kc * 128 + s * 64;         // byte offset of k-slice
                bf16x8 bR[2], bL[2], aF[5];
                bR[0] = *reinterpret_cast<const bf16x8*>(bR0 + kb);
                bR[1] = *reinterpret_cast<const bf16x8*>(bR1 + kb);
                bL[0] = *reinterpret_cast<const bf16x8*>(bL0 + kb);
                bL[1] = *reinterpret_cast<const bf16x8*>(bL1 + kb);
                #pragma unroll
                for (int m = 0; m < 5; ++m) {
                    // m==4 only rows 64/65 are consumed downstream; clamp so all
                    // LDS reads stay inside the 66-row A-tile allocation.
                    int row = (m == 4) ? (64 + (cl & 1)) : (m * 16 + cl);
                    int off = row * ROWSTR + kb + g * 16;
                    off ^= (row & 7) << 4;
                    aF[m] = *reinterpret_cast<const bf16x8*>(
                        reinterpret_cast<const char*>(ldsA) + off);
                }
                #pragma unroll
                for (int m = 0; m < 5; ++m) {
                    acc[m][0] = __builtin_amdgcn_mfma_f32_16x16x32_bf16(
                        aF[m], bR[0], acc[m][0], 0, 0, 0);
                    acc[m][1] = __builtin_amdgcn_mfma_f32_16x16x32_bf16(
                        aF[m], bR[1], acc[m][1], 0, 0, 0);
                }
                accU[0] = __builtin_amdgcn_mfma_f32_16x16x32_bf16(
                    aF[4], bL[0], accU[0], 0, 0, 0);
                accU[1] = __builtin_amdgcn_mfma_f32_16x16x32_bf16(
                    aF[4], bL[1], accU[1], 0, 0, 0);
            }
        }

        // epilogue (C/D: col=lane&15, row=(lane>>4)*4+reg)
        float contrib = 0.f;
        #pragma unroll
        for (int nf = 0; nf < 2; ++nf) {
            int c = cbase + nf * 16 + cl;
            float wl  = W2l[c] * (1.0f / 65.0f);
            float w2  = W2r[c];
            float uc  = __shfl(accU[nf][1], cl, 64) + b1[c];   // A-row 65 -> C-row 1
            float ps = 0.f;
            #pragma unroll
            for (int m = 0; m < 4; ++m)
                #pragma unroll
                for (int v = 0; v < 4; ++v)
                    ps += fmaxf(acc[m][nf][v] + uc, 0.f);      // rows 0..63
            {
                float hh = fmaxf(acc[4][nf][0] + uc, 0.f);     // row 64 (g==0,v==0 only)
                ps += (g == 0) ? hh : 0.f;
            }
            contrib += wl * ps;
            if (g == 0) {                                       // j==0 head term (row 0)
                float h0 = fmaxf(acc[0][nf][0] + uc, 0.f);
                contrib += w2 * h0;
            }
        }
        #pragma unroll
        for (int mask = 1; mask < 64; mask <<= 1)
            contrib += __shfl_xor(contrib, mask, 64);
        if (lane == 0) atomicAdd(&dout[b], contrib);
    }
}

// ---------------------------------------------------------------------------
extern "C" void kernel_launch(void* const* d_in, const int* in_sizes, int n_in,
                              void* d_out, int out_size, void* d_ws, size_t ws_size,
                              hipStream_t stream) {
    const float* inputs  = (const float*)d_in[0];
    const float* coords  = (const float*)d_in[1];
    const float* targets = (const float*)d_in[2];
    const int*   lens    = (const int*)d_in[3];
    const float* W1l     = (const float*)d_in[4];
    const float* W1r     = (const float*)d_in[5];
    const float* b1      = (const float*)d_in[6];
    const float* W2l     = (const float*)d_in[7];
    const float* W2r     = (const float*)d_in[8];
    const float* b2      = (const float*)d_in[9];
    float* dout = (float*)d_out;

    unsigned short* Wb = (unsigned short*)d_ws;   // 1024x256 bf16 = 512 KiB

    convw_kernel<<<dim3(2 * HDIM * FDIM / (256 * 8)), dim3(256), 0, stream>>>(
        W1r, W1l, Wb);

    fused_kernel<<<dim3(NBATCH), dim3(256), 0, stream>>>(
        inputs, coords, targets, lens, Wb, b1, W2l, W2r, b2, dout);
}

// Round 2
// 94.426 us; speedup vs baseline: 1.6851x; 1.6851x over previous
//
#include <hip/hip_runtime.h>
#include <hip/hip_bf16.h>
#include <stdint.h>

typedef __attribute__((ext_vector_type(8))) __bf16 bf16x8;
typedef __attribute__((ext_vector_type(4))) float f32x4;

// Problem constants (B=1024, L=512, F=256, H=512, K=64)
#define NBATCH 1024
#define SEQL   512
#define FDIM   256
#define HDIM   512
#define KNN    64
#define NODES  65
#define ROWSTR 512           // bytes per A-tile row (256 bf16)

__device__ __forceinline__ unsigned short f32_bf16(float f) {
    unsigned int u = __float_as_uint(f);
    unsigned int r = u + 0x7FFFu + ((u >> 16) & 1u);
    return (unsigned short)(r >> 16);
}

// ---------------------------------------------------------------------------
// Kernel 1: convert W1r and W1l to bf16 into Wb rows [0..511]=W1r, [512..1023]=W1l
// (verbatim round-3, validated)
// ---------------------------------------------------------------------------
__global__ __launch_bounds__(256) void convw_kernel(
    const float* __restrict__ W1r, const float* __restrict__ W1l,
    unsigned short* __restrict__ Wb)
{
    int i = (blockIdx.x * 256 + threadIdx.x) * 8;      // [0, 262144)
    const float* src = (i < HDIM * FDIM) ? (W1r + i) : (W1l + (i - HDIM * FDIM));
    float4 a = *reinterpret_cast<const float4*>(src);
    float4 c = *reinterpret_cast<const float4*>(src + 4);
    uint4 t;
    t.x = (unsigned)f32_bf16(a.x) | ((unsigned)f32_bf16(a.y) << 16);
    t.y = (unsigned)f32_bf16(a.z) | ((unsigned)f32_bf16(a.w) << 16);
    t.z = (unsigned)f32_bf16(c.x) | ((unsigned)f32_bf16(c.y) << 16);
    t.w = (unsigned)f32_bf16(c.z) | ((unsigned)f32_bf16(c.w) << 16);
    *reinterpret_cast<uint4*>(Wb + i) = t;
}

// ---------------------------------------------------------------------------
// Kernel 2 (fused, one 512-thread block per batch) — champion structure.
// Phases: bitonic top-64 -> float4 gather into swizzled bf16 LDS A-tile
// (rows 0..64, row 65 = aggr1) -> per-wave register-B GEMM -> fused epilogue.
// Only change this round: gather issues all 9 loads before converting/storing
// (9-deep ILP; was 4-deep) to cover HBM latency.
// ---------------------------------------------------------------------------
__global__ __launch_bounds__(512, 4) void fused_kernel(
    const float* __restrict__ inputs,   // [B,L,F]
    const float* __restrict__ coords,   // [B,L,2]
    const float* __restrict__ targets,  // [B,L,1]
    const int*   __restrict__ lens,     // [B]
    const unsigned short* __restrict__ Wb, // [1024,256] bf16: W1r then W1l
    const float* __restrict__ b1,       // [H]
    const float* __restrict__ W2l,      // [H]
    const float* __restrict__ W2r,      // [H]
    const float* __restrict__ b2,       // [1]
    float* __restrict__ dout)           // [2048]
{
    __shared__ unsigned long long keys[512];
    __shared__ int idxs[KNN];
    __shared__ __align__(16) float4 part[8][64];              // 8 KiB
    __shared__ __align__(16) unsigned short ldsA[66 * FDIM];  // 33 KiB, swizzled

    const int b   = blockIdx.x;
    const int tid = threadIdx.x;
    const float* cb = coords + (size_t)b * (SEQL * 2);
    const float qx = cb[0], qy = cb[1];
    const int len = lens[b];

    // ---- phase 1: keys + bitonic sort (ascending) — verbatim ----
    unsigned long long key;
    if (tid < SEQL - 1 && tid < len - 1) {
        float dx = cb[2 * (tid + 1)]     - qx;
        float dy = cb[2 * (tid + 1) + 1] - qy;
        float d2 = dx * dx + dy * dy;
        key = ((unsigned long long)__float_as_uint(d2) << 32) | (unsigned int)tid;
    } else {
        key = ~0ull;
    }

    for (int k = 2; k <= 512; k <<= 1) {
        for (int j = k >> 1; j >= 64; j >>= 1) {          // cross-wave via LDS
            keys[tid] = key;
            __syncthreads();
            unsigned long long other = keys[tid ^ j];
            bool takemin = (((tid & j) == 0) == ((tid & k) == 0));
            key = (takemin == (key < other)) ? key : other;
            __syncthreads();
        }
        for (int j = ((k >> 1) > 32 ? 32 : (k >> 1)); j >= 1; j >>= 1) {  // in-wave
            unsigned long long other = __shfl_xor(key, j, 64);
            bool takemin = (((tid & j) == 0) == ((tid & k) == 0));
            key = (takemin == (key < other)) ? key : other;
        }
    }

    if (tid < KNN) idxs[tid] = (int)(unsigned int)(key & 0xffffffffull);
    if (tid == 0) {
        dout[b] = b2[0];                                  // bias init; epilogue accumulates
        dout[NBATCH + b] = targets[(size_t)b * SEQL];     // y head
    }
    __syncthreads();

    const int c4 = tid & 63;          // float4 column 0..63
    const int g0 = tid >> 6;          // row phase 0..7

#define STROW(row, v) do {                                                   \
    int off_ = (row) * ROWSTR + c4 * 8; off_ ^= ((row) & 7) << 4;            \
    uint2 pk_;                                                               \
    pk_.x = (unsigned)f32_bf16((v).x) | ((unsigned)f32_bf16((v).y) << 16);   \
    pk_.y = (unsigned)f32_bf16((v).z) | ((unsigned)f32_bf16((v).w) << 16);   \
    *reinterpret_cast<uint2*>(reinterpret_cast<char*>(ldsA) + off_) = pk_;   \
} while (0)

    // ---- phase 2: gather, rows r = g0+8q (+row 64 by g0==0), 9-deep ILP ----
    {
        const float* xb = inputs + (size_t)b * SEQL * FDIM + c4 * 4;
        int srcs[8];
        #pragma unroll
        for (int q = 0; q < 8; ++q) {
            int r = g0 + q * 8;
            srcs[q] = (r == 0) ? 0 : idxs[r - 1];
        }
        int src8 = idxs[63];                 // only used by g0==0
        float4 v[8];
        #pragma unroll
        for (int q = 0; q < 8; ++q)
            v[q] = *reinterpret_cast<const float4*>(xb + (size_t)srcs[q] * FDIM);
        float4 v8;
        if (g0 == 0)
            v8 = *reinterpret_cast<const float4*>(xb + (size_t)src8 * FDIM);

        float4 sum = {0.f, 0.f, 0.f, 0.f};
        #pragma unroll
        for (int q = 0; q < 8; ++q) {
            int r = g0 + q * 8;
            sum.x += v[q].x; sum.y += v[q].y; sum.z += v[q].z; sum.w += v[q].w;
            STROW(r, v[q]);
        }
        if (g0 == 0) {
            sum.x += v8.x; sum.y += v8.y; sum.z += v8.z; sum.w += v8.w;
            STROW(64, v8);
        }
        part[g0][c4] = sum;
    }
    __syncthreads();
    if (tid < 64) {                              // row 65 = aggr1 (bf16)
        float sx = 0.f, sy = 0.f, sz = 0.f, sw = 0.f;
        #pragma unroll
        for (int q = 0; q < 8; ++q) {
            float4 p = part[q][tid];
            sx += p.x; sy += p.y; sz += p.z; sw += p.w;
        }
        const float inv = 1.0f / 65.0f;
        uint2 pk;
        pk.x = (unsigned)f32_bf16(sx * inv) | ((unsigned)f32_bf16(sy * inv) << 16);
        pk.y = (unsigned)f32_bf16(sz * inv) | ((unsigned)f32_bf16(sw * inv) << 16);
        int off = 65 * ROWSTR + tid * 8; off ^= 0x10;     // (65&7)<<4
        *reinterpret_cast<uint2*>(reinterpret_cast<char*>(ldsA) + off) = pk;
    }
    __syncthreads();
#undef STROW

    // ---- phase 3: GEMM + epilogue, per wave over 2 passes of 32 cols — verbatim
    const int lane = tid & 63;
    const int w    = tid >> 6;
    const int cl   = lane & 15, g = lane >> 4;

    #pragma unroll
    for (int p = 0; p < 2; ++p) {
        const int cbase = w * 64 + p * 32;

        f32x4 acc[5][2], accU[2];
        #pragma unroll
        for (int m = 0; m < 5; ++m) {
            acc[m][0] = f32x4{0.f, 0.f, 0.f, 0.f};
            acc[m][1] = f32x4{0.f, 0.f, 0.f, 0.f};
        }
        accU[0] = f32x4{0.f, 0.f, 0.f, 0.f};
        accU[1] = f32x4{0.f, 0.f, 0.f, 0.f};

        const char* bR0 = (const char*)Wb + (size_t)(cbase + cl) * ROWSTR + g * 16;
        const char* bR1 = bR0 + 16 * ROWSTR;
        const char* bL0 = bR0 + (size_t)HDIM * ROWSTR;       // W1l rows at +512
        const char* bL1 = bL0 + 16 * ROWSTR;

        #pragma unroll
        for (int kc = 0; kc < 4; ++kc) {
            #pragma unroll
            for (int s = 0; s < 2; ++s) {
                const int kb = kc * 128 + s * 64;         // byte offset of k-slice
                bf16x8 bR[2], bL[2], aF[5];
                bR[0] = *reinterpret_cast<const bf16x8*>(bR0 + kb);
                bR[1] = *reinterpret_cast<const bf16x8*>(bR1 + kb);
                bL[0] = *reinterpret_cast<const bf16x8*>(bL0 + kb);
                bL[1] = *reinterpret_cast<const bf16x8*>(bL1 + kb);
                #pragma unroll
                for (int m = 0; m < 5; ++m) {
                    int row = m * 16 + cl;
                    int off = row * ROWSTR + kb + g * 16;
                    off ^= (row & 7) << 4;
                    aF[m] = *reinterpret_cast<const bf16x8*>(
                        reinterpret_cast<const char*>(ldsA) + off);
                }
                #pragma unroll
                for (int m = 0; m < 5; ++m) {
                    acc[m][0] = __builtin_amdgcn_mfma_f32_16x16x32_bf16(
                        aF[m], bR[0], acc[m][0], 0, 0, 0);
                    acc[m][1] = __builtin_amdgcn_mfma_f32_16x16x32_bf16(
                        aF[m], bR[1], acc[m][1], 0, 0, 0);
                }
                accU[0] = __builtin_amdgcn_mfma_f32_16x16x32_bf16(
                    aF[4], bL[0], accU[0], 0, 0, 0);
                accU[1] = __builtin_amdgcn_mfma_f32_16x16x32_bf16(
                    aF[4], bL[1], accU[1], 0, 0, 0);
            }
        }

        // epilogue (C/D: col=lane&15, row=(lane>>4)*4+reg)
        float contrib = 0.f;
        #pragma unroll
        for (int nf = 0; nf < 2; ++nf) {
            int c = cbase + nf * 16 + cl;
            float wl  = W2l[c] * (1.0f / 65.0f);
            float w2  = W2r[c];
            float uc  = __shfl(accU[nf][1], cl, 64) + b1[c];   // A-row 65 -> C-row 1
            float ps = 0.f;
            #pragma unroll
            for (int m = 0; m < 4; ++m)
                #pragma unroll
                for (int v = 0; v < 4; ++v)
                    ps += fmaxf(acc[m][nf][v] + uc, 0.f);      // rows 0..63
            {
                float hh = fmaxf(acc[4][nf][0] + uc, 0.f);     // row 64 (g==0,v==0 only)
                ps += (g == 0) ? hh : 0.f;
            }
            contrib += wl * ps;
            if (g == 0) {                                       // j==0 head term (row 0)
                float h0 = fmaxf(acc[0][nf][0] + uc, 0.f);
                contrib += w2 * h0;
            }
        }
        #pragma unroll
        for (int mask = 1; mask < 64; mask <<= 1)
            contrib += __shfl_xor(contrib, mask, 64);
        if (lane == 0) atomicAdd(&dout[b], contrib);
    }
}

// ---------------------------------------------------------------------------
extern "C" void kernel_launch(void* const* d_in, const int* in_sizes, int n_in,
                              void* d_out, int out_size, void* d_ws, size_t ws_size,
                              hipStream_t stream) {
    const float* inputs  = (const float*)d_in[0];
    const float* coords  = (const float*)d_in[1];
    const float* targets = (const float*)d_in[2];
    const int*   lens    = (const int*)d_in[3];
    const float* W1l     = (const float*)d_in[4];
    const float* W1r     = (const float*)d_in[5];
    const float* b1      = (const float*)d_in[6];
    const float* W2l     = (const float*)d_in[7];
    const float* W2r     = (const float*)d_in[8];
    const float* b2      = (const float*)d_in[9];
    float* dout = (float*)d_out;

    unsigned short* Wb = (unsigned short*)d_ws;   // 1024x256 bf16 = 512 KiB

    convw_kernel<<<dim3(2 * HDIM * FDIM / (256 * 8)), dim3(256), 0, stream>>>(
        W1r, W1l, Wb);

    fused_kernel<<<dim3(NBATCH), dim3(512), 0, stream>>>(
        inputs, coords, targets, lens, Wb, b1, W2l, W2r, b2, dout);
}

// Round 3
// 63.773 us; speedup vs baseline: 2.4951x; 1.4806x over previous
//
#include <hip/hip_runtime.h>
#include <hip/hip_bf16.h>
#include <stdint.h>

typedef __attribute__((ext_vector_type(8))) __bf16 bf16x8;
typedef __attribute__((ext_vector_type(4))) float f32x4;

// Problem constants (B=1024, L=512, F=256, H=512, K=64)
#define NBATCH 1024
#define SEQL   512
#define FDIM   256
#define HDIM   512
#define KNN    64
#define NODES  65
#define ROWSTR 512           // bytes per A-tile row (256 bf16)

__device__ __forceinline__ unsigned short f32_bf16(float f) {
    unsigned int u = __float_as_uint(f);
    unsigned int r = u + 0x7FFFu + ((u >> 16) & 1u);
    return (unsigned short)(r >> 16);
}

// ---------------------------------------------------------------------------
// Kernel 1: convert W1r/W1l to bf16 in MFMA-fragment-major layout:
//   chunk t = ((mat*32 + cb16)*8 + kidx)*64 + lane   (16 bytes per chunk)
// where mat: 0=W1r 1=W1l, cb16 = output-col block of 16, kidx = k-slice of 32
// bf16 (kc*2+s), lane = g*16+cl holds cols [cb16*16+cl], k-bytes [kidx*64+g*16).
// A wave's B-fragment load is then one contiguous 1KB segment.
// ---------------------------------------------------------------------------
__global__ __launch_bounds__(256) void convw_kernel(
    const float* __restrict__ W1r, const float* __restrict__ W1l,
    unsigned short* __restrict__ Wb)
{
    int i = blockIdx.x * 256 + threadIdx.x;   // 0..32767, one 16B output chunk
    int f = i * 8;                            // first source float in [W1r;W1l]
    int row = f >> 8;                         // 0..1023 (concat row)
    int col = f & 255;                        // multiple of 8
    int mat = row >> 9;
    int r   = row & 511;
    int j   = col >> 3;                       // 0..31
    int g   = j & 3, kidx = j >> 2;
    int cl  = r & 15, cb16 = r >> 4;
    int lane = g * 16 + cl;

    const float* src = (mat ? W1l : W1r) + (size_t)r * FDIM + col;
    float4 a = *reinterpret_cast<const float4*>(src);
    float4 c = *reinterpret_cast<const float4*>(src + 4);
    uint4 t;
    t.x = (unsigned)f32_bf16(a.x) | ((unsigned)f32_bf16(a.y) << 16);
    t.y = (unsigned)f32_bf16(a.z) | ((unsigned)f32_bf16(a.w) << 16);
    t.z = (unsigned)f32_bf16(c.x) | ((unsigned)f32_bf16(c.y) << 16);
    t.w = (unsigned)f32_bf16(c.z) | ((unsigned)f32_bf16(c.w) << 16);

    size_t tchunk = (size_t)((mat * 32 + cb16) * 8 + kidx) * 64 + lane;
    *reinterpret_cast<uint4*>(Wb + tchunk * 8) = t;
}

// ---------------------------------------------------------------------------
// Kernel 2 (fused, one 512-thread block per batch) — champion structure.
// Phases: bitonic top-64 -> float4 gather into swizzled bf16 LDS A-tile
// (rows 0..64, row 65 = aggr1) -> per-wave register-B GEMM -> fused epilogue.
// Change this round: B loads use the fragment-major Wb layout (coalesced 1KB
// wave-loads instead of 16-segment 512B-strided gathers).
// ---------------------------------------------------------------------------
__global__ __launch_bounds__(512, 4) void fused_kernel(
    const float* __restrict__ inputs,   // [B,L,F]
    const float* __restrict__ coords,   // [B,L,2]
    const float* __restrict__ targets,  // [B,L,1]
    const int*   __restrict__ lens,     // [B]
    const unsigned short* __restrict__ Wb, // fragment-major, 512 KiB
    const float* __restrict__ b1,       // [H]
    const float* __restrict__ W2l,      // [H]
    const float* __restrict__ W2r,      // [H]
    const float* __restrict__ b2,       // [1]
    float* __restrict__ dout)           // [2048]
{
    __shared__ unsigned long long keys[512];
    __shared__ int idxs[KNN];
    __shared__ __align__(16) float4 part[8][64];              // 8 KiB
    __shared__ __align__(16) unsigned short ldsA[66 * FDIM];  // 33 KiB, swizzled

    const int b   = blockIdx.x;
    const int tid = threadIdx.x;
    const float* cb = coords + (size_t)b * (SEQL * 2);
    const float qx = cb[0], qy = cb[1];
    const int len = lens[b];

    // ---- phase 1: keys + bitonic sort (ascending) — verbatim ----
    unsigned long long key;
    if (tid < SEQL - 1 && tid < len - 1) {
        float dx = cb[2 * (tid + 1)]     - qx;
        float dy = cb[2 * (tid + 1) + 1] - qy;
        float d2 = dx * dx + dy * dy;
        key = ((unsigned long long)__float_as_uint(d2) << 32) | (unsigned int)tid;
    } else {
        key = ~0ull;
    }

    for (int k = 2; k <= 512; k <<= 1) {
        for (int j = k >> 1; j >= 64; j >>= 1) {          // cross-wave via LDS
            keys[tid] = key;
            __syncthreads();
            unsigned long long other = keys[tid ^ j];
            bool takemin = (((tid & j) == 0) == ((tid & k) == 0));
            key = (takemin == (key < other)) ? key : other;
            __syncthreads();
        }
        for (int j = ((k >> 1) > 32 ? 32 : (k >> 1)); j >= 1; j >>= 1) {  // in-wave
            unsigned long long other = __shfl_xor(key, j, 64);
            bool takemin = (((tid & j) == 0) == ((tid & k) == 0));
            key = (takemin == (key < other)) ? key : other;
        }
    }

    if (tid < KNN) idxs[tid] = (int)(unsigned int)(key & 0xffffffffull);
    if (tid == 0) {
        dout[b] = b2[0];                                  // bias init; epilogue accumulates
        dout[NBATCH + b] = targets[(size_t)b * SEQL];     // y head
    }
    __syncthreads();

    const int c4 = tid & 63;          // float4 column 0..63
    const int g0 = tid >> 6;          // row phase 0..7

#define STROW(row, v) do {                                                   \
    int off_ = (row) * ROWSTR + c4 * 8; off_ ^= ((row) & 7) << 4;            \
    uint2 pk_;                                                               \
    pk_.x = (unsigned)f32_bf16((v).x) | ((unsigned)f32_bf16((v).y) << 16);   \
    pk_.y = (unsigned)f32_bf16((v).z) | ((unsigned)f32_bf16((v).w) << 16);   \
    *reinterpret_cast<uint2*>(reinterpret_cast<char*>(ldsA) + off_) = pk_;   \
} while (0)

    // ---- phase 2: gather, rows r = g0+8q (+row 64 by g0==0), 9-deep ILP ----
    {
        const float* xb = inputs + (size_t)b * SEQL * FDIM + c4 * 4;
        int srcs[8];
        #pragma unroll
        for (int q = 0; q < 8; ++q) {
            int r = g0 + q * 8;
            srcs[q] = (r == 0) ? 0 : idxs[r - 1];
        }
        int src8 = idxs[63];                 // only used by g0==0
        float4 v[8];
        #pragma unroll
        for (int q = 0; q < 8; ++q)
            v[q] = *reinterpret_cast<const float4*>(xb + (size_t)srcs[q] * FDIM);
        float4 v8;
        if (g0 == 0)
            v8 = *reinterpret_cast<const float4*>(xb + (size_t)src8 * FDIM);

        float4 sum = {0.f, 0.f, 0.f, 0.f};
        #pragma unroll
        for (int q = 0; q < 8; ++q) {
            int r = g0 + q * 8;
            sum.x += v[q].x; sum.y += v[q].y; sum.z += v[q].z; sum.w += v[q].w;
            STROW(r, v[q]);
        }
        if (g0 == 0) {
            sum.x += v8.x; sum.y += v8.y; sum.z += v8.z; sum.w += v8.w;
            STROW(64, v8);
        }
        part[g0][c4] = sum;
    }
    __syncthreads();
    if (tid < 64) {                              // row 65 = aggr1 (bf16)
        float sx = 0.f, sy = 0.f, sz = 0.f, sw = 0.f;
        #pragma unroll
        for (int q = 0; q < 8; ++q) {
            float4 p = part[q][tid];
            sx += p.x; sy += p.y; sz += p.z; sw += p.w;
        }
        const float inv = 1.0f / 65.0f;
        uint2 pk;
        pk.x = (unsigned)f32_bf16(sx * inv) | ((unsigned)f32_bf16(sy * inv) << 16);
        pk.y = (unsigned)f32_bf16(sz * inv) | ((unsigned)f32_bf16(sw * inv) << 16);
        int off = 65 * ROWSTR + tid * 8; off ^= 0x10;     // (65&7)<<4
        *reinterpret_cast<uint2*>(reinterpret_cast<char*>(ldsA) + off) = pk;
    }
    __syncthreads();
#undef STROW

    // ---- phase 3: GEMM + epilogue, per wave over 2 passes of 32 cols ----
    const int lane = tid & 63;
    const int w    = tid >> 6;
    const int cl   = lane & 15, g = lane >> 4;

    #pragma unroll
    for (int p = 0; p < 2; ++p) {
        const int cbase = w * 64 + p * 32;

        f32x4 acc[5][2], accU[2];
        #pragma unroll
        for (int m = 0; m < 5; ++m) {
            acc[m][0] = f32x4{0.f, 0.f, 0.f, 0.f};
            acc[m][1] = f32x4{0.f, 0.f, 0.f, 0.f};
        }
        accU[0] = f32x4{0.f, 0.f, 0.f, 0.f};
        accU[1] = f32x4{0.f, 0.f, 0.f, 0.f};

        // fragment-major B: block index blkR = cbase/16; bR1 = blkR+1;
        // W1l at block +32. Each load: contiguous 1KB across the wave.
        const int blkR = w * 4 + p * 2;
        const char* base = (const char*)Wb;
        const size_t oR0 = (size_t)(blkR * 8) * 1024 + (size_t)lane * 16;
        const size_t oR1 = oR0 + 8 * 1024;
        const size_t oL0 = oR0 + (size_t)32 * 8 * 1024;
        const size_t oL1 = oL0 + 8 * 1024;

        #pragma unroll
        for (int kc = 0; kc < 4; ++kc) {
            #pragma unroll
            for (int s = 0; s < 2; ++s) {
                const int kb  = kc * 128 + s * 64;        // byte offset of k-slice (A)
                const int kfr = (kc * 2 + s) * 1024;      // fragment-major B offset
                bf16x8 bR[2], bL[2], aF[5];
                bR[0] = *reinterpret_cast<const bf16x8*>(base + oR0 + kfr);
                bR[1] = *reinterpret_cast<const bf16x8*>(base + oR1 + kfr);
                bL[0] = *reinterpret_cast<const bf16x8*>(base + oL0 + kfr);
                bL[1] = *reinterpret_cast<const bf16x8*>(base + oL1 + kfr);
                #pragma unroll
                for (int m = 0; m < 5; ++m) {
                    int row = m * 16 + cl;
                    int off = row * ROWSTR + kb + g * 16;
                    off ^= (row & 7) << 4;
                    aF[m] = *reinterpret_cast<const bf16x8*>(
                        reinterpret_cast<const char*>(ldsA) + off);
                }
                #pragma unroll
                for (int m = 0; m < 5; ++m) {
                    acc[m][0] = __builtin_amdgcn_mfma_f32_16x16x32_bf16(
                        aF[m], bR[0], acc[m][0], 0, 0, 0);
                    acc[m][1] = __builtin_amdgcn_mfma_f32_16x16x32_bf16(
                        aF[m], bR[1], acc[m][1], 0, 0, 0);
                }
                accU[0] = __builtin_amdgcn_mfma_f32_16x16x32_bf16(
                    aF[4], bL[0], accU[0], 0, 0, 0);
                accU[1] = __builtin_amdgcn_mfma_f32_16x16x32_bf16(
                    aF[4], bL[1], accU[1], 0, 0, 0);
            }
        }

        // epilogue (C/D: col=lane&15, row=(lane>>4)*4+reg)
        float contrib = 0.f;
        #pragma unroll
        for (int nf = 0; nf < 2; ++nf) {
            int c = cbase + nf * 16 + cl;
            float wl  = W2l[c] * (1.0f / 65.0f);
            float w2  = W2r[c];
            float uc  = __shfl(accU[nf][1], cl, 64) + b1[c];   // A-row 65 -> C-row 1
            float ps = 0.f;
            #pragma unroll
            for (int m = 0; m < 4; ++m)
                #pragma unroll
                for (int v = 0; v < 4; ++v)
                    ps += fmaxf(acc[m][nf][v] + uc, 0.f);      // rows 0..63
            {
                float hh = fmaxf(acc[4][nf][0] + uc, 0.f);     // row 64 (g==0,v==0 only)
                ps += (g == 0) ? hh : 0.f;
            }
            contrib += wl * ps;
            if (g == 0) {                                       // j==0 head term (row 0)
                float h0 = fmaxf(acc[0][nf][0] + uc, 0.f);
                contrib += w2 * h0;
            }
        }
        #pragma unroll
        for (int mask = 1; mask < 64; mask <<= 1)
            contrib += __shfl_xor(contrib, mask, 64);
        if (lane == 0) atomicAdd(&dout[b], contrib);
    }
}

// ---------------------------------------------------------------------------
extern "C" void kernel_launch(void* const* d_in, const int* in_sizes, int n_in,
                              void* d_out, int out_size, void* d_ws, size_t ws_size,
                              hipStream_t stream) {
    const float* inputs  = (const float*)d_in[0];
    const float* coords  = (const float*)d_in[1];
    const float* targets = (const float*)d_in[2];
    const int*   lens    = (const int*)d_in[3];
    const float* W1l     = (const float*)d_in[4];
    const float* W1r     = (const float*)d_in[5];
    const float* b1      = (const float*)d_in[6];
    const float* W2l     = (const float*)d_in[7];
    const float* W2r     = (const float*)d_in[8];
    const float* b2      = (const float*)d_in[9];
    float* dout = (float*)d_out;

    unsigned short* Wb = (unsigned short*)d_ws;   // 512 KiB, fragment-major

    convw_kernel<<<dim3(2 * HDIM * FDIM / (256 * 8)), dim3(256), 0, stream>>>(
        W1r, W1l, Wb);

    fused_kernel<<<dim3(NBATCH), dim3(512), 0, stream>>>(
        inputs, coords, targets, lens, Wb, b1, W2l, W2r, b2, dout);
}